// Round 15
// baseline (358.592 us; speedup 1.0000x reference)
//
#include <hip/hip_runtime.h>

// B=4, C=16, G=8, KK=9.  Levels: 256x256, 254x254, 252x252.
// Feature maps: channel-last BF16 [b][px][16]; unr features ALSO planar f32
// [b][c][y][x] for deform gather.
// deform R15: 20x20x16ch block-local window staged in LDS (pair-interleaved);
// wave-uniform in-tile fast path (ds_read_b64 per corner), global fallback.

typedef __attribute__((ext_vector_type(8))) short bf16x8;
typedef __attribute__((ext_vector_type(4))) float f32x4;
typedef __attribute__((ext_vector_type(2))) float f32x2;

__device__ inline unsigned short f2bf(float f) {
    union { float f; unsigned int u; } x; x.f = f;
    unsigned int u = x.u;
    u += 0x7fffu + ((u >> 16) & 1u);   // RNE
    return (unsigned short)(u >> 16);
}
__device__ inline float bf2f(unsigned short u) {
    union { unsigned int i; float f; } x; x.i = ((unsigned int)u) << 16;
    return x.f;
}
__device__ inline f32x2 ld2(const float* p) {   // 8B load, 4B-align safe
    f32x2 v;
    __builtin_memcpy(&v, p, 8);
    return v;
}

// Bijective XCD-aware block swizzle (T1).  Requires nwg % 8 == 0.
__device__ inline void xcd_swz(int& bx, int& by, int& bz) {
    const int gx = gridDim.x, gy = gridDim.y, gz = gridDim.z;
    const int hw = blockIdx.x + gx * (blockIdx.y + gy * blockIdx.z);
    const int per = (gx * gy * gz) >> 3;
    const int lg = (hw & 7) * per + (hw >> 3);
    bz = lg / (gx * gy);
    const int rem = lg - bz * gx * gy;
    by = rem / gx;
    bx = rem - by * gx;
}

// ---------------- conv1: 3->16, pad1, relu; both images in one launch ----------------
__global__ __launch_bounds__(256) void conv1_kernel(
    const float* __restrict__ ref, const float* __restrict__ unr,
    const float* __restrict__ w, const float* __restrict__ bias,
    unsigned short* __restrict__ outA, unsigned short* __restrict__ outB,
    float* __restrict__ pU)
{
    const int H = 256, W = 256;
    __shared__ float sIn[3][18][18];
    const int tx = threadIdx.x, ty = threadIdx.y;
    const int tid = ty * 16 + tx;
    const int bx = blockIdx.x, by = blockIdx.y, bz8 = blockIdx.z;
    const int isUnr = bz8 >> 2, bb = bz8 & 3;
    const float* in = isUnr ? unr : ref;
    unsigned short* outCL = isUnr ? outB : outA;
    const int x0 = bx * 16 - 1, y0 = by * 16 - 1;

    for (int idx = tid; idx < 3 * 324; idx += 256) {
        int c = idx / 324, rem = idx % 324, r = rem / 18, col = rem % 18;
        int gy = y0 + r, gx = x0 + col;
        float v = 0.f;
        if (gy >= 0 && gy < H && gx >= 0 && gx < W)
            v = in[((bb * 3 + c) * H + gy) * W + gx];
        sIn[c][r][col] = v;
    }
    __syncthreads();

    const int y = by * 16 + ty, x = bx * 16 + tx;
    float acc[16];
#pragma unroll
    for (int o = 0; o < 16; o++) acc[o] = bias[o];
#pragma unroll
    for (int ci = 0; ci < 3; ci++) {
        float xv[9];
#pragma unroll
        for (int r = 0; r < 3; r++)
#pragma unroll
            for (int c = 0; c < 3; c++)
                xv[r * 3 + c] = sIn[ci][ty + r][tx + c];
#pragma unroll
        for (int o = 0; o < 16; o++) {
            const float* wp = w + (o * 3 + ci) * 9;
#pragma unroll
            for (int u = 0; u < 9; u++) acc[o] += wp[u] * xv[u];
        }
    }
#pragma unroll
    for (int o = 0; o < 16; o++) acc[o] = fmaxf(acc[o], 0.f);

    const size_t HW = (size_t)H * W;
    unsigned short tmp[16];
#pragma unroll
    for (int o = 0; o < 16; o++) tmp[o] = f2bf(acc[o]);
    unsigned short* op = outCL + ((size_t)bb * HW + (size_t)y * W + x) * 16;
    *(bf16x8*)(op) = *(bf16x8*)&tmp[0];
    *(bf16x8*)(op + 8) = *(bf16x8*)&tmp[8];
    if (isUnr) {
#pragma unroll
        for (int o = 0; o < 16; o++)
            pU[((size_t)(bb * 16 + o) * H + y) * W + x] = acc[o];
    }
}

// ---------------- MFMA conv 16->16, pad0, relu; bf16 CL in/out; both images ----------------
__global__ __launch_bounds__(512, 4) void c16m_kernel(
    const unsigned short* __restrict__ inA, const unsigned short* __restrict__ inB,
    const unsigned short* __restrict__ Bc16, const float* __restrict__ bias,
    unsigned short* __restrict__ outA, unsigned short* __restrict__ outB,
    float* __restrict__ pU, int Hout, int Wout)
{
    const int Hin = Hout + 2, Win = Wout + 2;
    __shared__ __align__(16) unsigned short sC[324 * 16];  // [r*18+c][16] bf16
    __shared__ float sT[16][16][17];                       // [yy][ch][x] padded
    const int tid = threadIdx.x;
    const int bx = blockIdx.x, by = blockIdx.y, bz8 = blockIdx.z;
    const int isUnr = bz8 >> 2, bz = bz8 & 3;
    const unsigned short* inCL = isUnr ? inB : inA;
    unsigned short* outCL = isUnr ? outB : outA;
    const int x0 = bx * 16, y0 = by * 16;

    for (int idx = tid; idx < 648; idx += 512) {
        int px = idx >> 1, half = idx & 1;
        int r = px / 18, c = px % 18;
        int gy = min(y0 + r, Hin - 1), gx = min(x0 + c, Win - 1);
        const bf16x8* p = (const bf16x8*)(inCL +
            (((size_t)bz * Hin * Win + (size_t)gy * Win + gx) * 16 + 8 * half));
        *(bf16x8*)&sC[px * 16 + 8 * half] = *p;
    }
    __syncthreads();

    const int w = tid >> 6, l = tid & 63;
    const int q = l >> 4, j16 = l & 15;
    const float bv = bias[j16];
    f32x4 acc0 = {bv, bv, bv, bv}, acc1 = {bv, bv, bv, bv};

#pragma unroll
    for (int t = 0; t < 5; ++t) {
        const int u = (t == 4) ? 8 : 2 * t + (q >> 1);
        const int dr = u / 3, dc = u % 3;
        bf16x8 a0 = *(const bf16x8*)&sC[(((w) + dr) * 18 + (j16 + dc)) * 16 + (q & 1) * 8];
        bf16x8 a1 = *(const bf16x8*)&sC[(((w + 8) + dr) * 18 + (j16 + dc)) * 16 + (q & 1) * 8];
        bf16x8 b = *(const bf16x8*)&Bc16[(t * 64 + l) * 8];
        acc0 = __builtin_amdgcn_mfma_f32_16x16x32_bf16(a0, b, acc0, 0, 0, 0);
        acc1 = __builtin_amdgcn_mfma_f32_16x16x32_bf16(a1, b, acc1, 0, 0, 0);
    }
#pragma unroll
    for (int r = 0; r < 4; ++r) { acc0[r] = fmaxf(acc0[r], 0.f); acc1[r] = fmaxf(acc1[r], 0.f); }

    const int yA = y0 + w, yB = y0 + w + 8;
    const size_t HWo = (size_t)Hout * Wout;
#pragma unroll
    for (int r = 0; r < 4; ++r) {
        int x = x0 + 4 * q + r;
        if (yA < Hout && x < Wout)
            outCL[((size_t)bz * HWo + (size_t)yA * Wout + x) * 16 + j16] = f2bf(acc0[r]);
        if (yB < Hout && x < Wout)
            outCL[((size_t)bz * HWo + (size_t)yB * Wout + x) * 16 + j16] = f2bf(acc1[r]);
    }

    if (isUnr) {
#pragma unroll
        for (int r = 0; r < 4; ++r) {
            sT[w][j16][4 * q + r] = acc0[r];
            sT[w + 8][j16][4 * q + r] = acc1[r];
        }
        __syncthreads();
        const int ch = tid >> 5, yy = (tid >> 1) & 15, half = tid & 1;
        const int yo = y0 + yy;
        if (yo < Hout) {
            float* dst = pU + ((size_t)(bz * 16 + ch) * Hout + yo) * Wout + x0 + half * 8;
#pragma unroll
            for (int i = 0; i < 8; ++i) {
                int x = x0 + half * 8 + i;
                if (x < Wout) dst[i] = sT[yy][ch][half * 8 + i];
            }
        }
    }
}

// ---------------- weight prep (offset conv B-frags + bias + dwT + c16 B-frags) ----------------
__global__ __launch_bounds__(512) void prep_kernel(
    const float* __restrict__ o1w, const float* __restrict__ o2w, const float* __restrict__ o3w,
    const float* __restrict__ o1b, const float* __restrict__ o2b, const float* __restrict__ o3b,
    const float* __restrict__ dw, const float* __restrict__ c2w, const float* __restrict__ c3w,
    unsigned short* __restrict__ Bfrag, float* __restrict__ biasPrep, float* __restrict__ dwT,
    unsigned short* __restrict__ Bc16)
{
    const int lvl = blockIdx.y;
    const float* Wt = (lvl == 0) ? o1w : (lvl == 1) ? o2w : o3w;
    const float* Bb = (lvl == 0) ? o1b : (lvl == 1) ? o2b : o3b;
    int idx = blockIdx.x * 512 + threadIdx.x;   // 81*512 = 41472
    int j = idx & 7;
    int l = (idx >> 3) & 63;
    int tu = idx >> 9;
    int t = tu / 9, u = tu % 9;
    int q = l >> 4, n16 = l & 15;
    int ci = 8 * q + j;
    int g = n16 >> 1, d = n16 & 1;
    int ch = g * 18 + t * 2 + d;
    Bfrag[lvl * 41472 + idx] = f2bf(Wt[(ch * 32 + ci) * 9 + u]);
    if (blockIdx.x == 0 && threadIdx.x < 144) {
        int n = threadIdx.x;
        int tt = n >> 4, nn = n & 15;
        biasPrep[lvl * 144 + n] = Bb[(nn >> 1) * 18 + tt * 2 + (nn & 1)];
    }
    if (lvl == 0 && blockIdx.x == 1) {
        for (int i = threadIdx.x; i < 2304; i += 512) {
            int c = i / 144, rem = i % 144, k = rem / 16, o = rem & 15;
            dwT[i] = dw[(o * 16 + c) * 9 + k];
        }
    }
    if (lvl == 2 && blockIdx.x >= 20 && blockIdx.x < 30) {
        int i2 = (blockIdx.x - 20) * 512 + threadIdx.x;   // 5120 = 2*2560
        int cw = i2 / 2560, rem = i2 % 2560;
        int jj = rem & 7, ll = (rem >> 3) & 63, tt = rem >> 9;
        int qq = ll >> 4, oo = ll & 15;
        int uu = (tt == 4) ? 8 : 2 * tt + (qq >> 1);
        int cc = (qq & 1) * 8 + jj;
        const float* wsel = cw ? c3w : c2w;
        float val = (tt == 4 && qq >= 2) ? 0.f : wsel[(oo * 16 + cc) * 9 + uu];
        Bc16[i2] = f2bf(val);
    }
}

// ---------------- MFMA offset conv -> bf16 offsets [tap][px][16]; B-panel in LDS ----------------
#define CP 40
__global__ __launch_bounds__(512, 4) void offconv_kernel(
    const unsigned short* __restrict__ refCL, const unsigned short* __restrict__ unrCL,
    const unsigned short* __restrict__ Bfrag, const float* __restrict__ biasPrep,
    unsigned short* __restrict__ offbuf, int bbBase, int BN, int H, int W)
{
    __shared__ __align__(16) unsigned short sIn[18 * 18 * CP];   // 25920 B
    __shared__ __align__(16) unsigned short sB[2][4608];         // 2 x 9216 B (one tap)
    const int tid = threadIdx.x;
    int bx, by, bz;
    xcd_swz(bx, by, bz);
    const int bb = bbBase + bz;
    const int x0 = bx * 16 - 1, y0 = by * 16 - 1;
    const size_t HW = (size_t)H * W;

    auto loadB = [&](int t, int buf) {
        const bf16x8* src = (const bf16x8*)(Bfrag + (size_t)t * 4608);
        bf16x8* dst = (bf16x8*)&sB[buf][0];
        dst[tid] = src[tid];
        if (tid < 64) dst[512 + tid] = src[512 + tid];
    };
    loadB(0, 0);

    for (int idx = tid; idx < 1296; idx += 512) {
        int px = idx >> 2, ch8 = idx & 3;
        int r = px / 18, c = px % 18;
        int gy = y0 + r, gx = x0 + c;
        bf16x8 v = {};
        if (gy >= 0 && gy < H && gx >= 0 && gx < W) {
            const unsigned short* src = (ch8 < 2) ? refCL : unrCL;
            v = *(const bf16x8*)(src + (((size_t)bb * HW + (size_t)gy * W + gx) * 16 + (ch8 & 1) * 8));
        }
        *(bf16x8*)&sIn[px * CP + ch8 * 8] = v;
    }
    __syncthreads();

    const int w = tid >> 6, l = tid & 63;
    const int q = l >> 4, j16 = l & 15;

    bf16x8 a0[9], a1[9];
#pragma unroll
    for (int u = 0; u < 9; ++u) {
        int dr = u / 3, dc = u % 3;
        a0[u] = *(const bf16x8*)&sIn[((w + dr) * 18 + (j16 + dc)) * CP + 8 * q];
        a1[u] = *(const bf16x8*)&sIn[((w + 8 + dr) * 18 + (j16 + dc)) * CP + 8 * q];
    }
    const int yA = by * 16 + w, yB = by * 16 + w + 8;

    float bvv[9];
#pragma unroll
    for (int t = 0; t < 9; ++t) bvv[t] = biasPrep[t * 16 + j16];

#pragma unroll 1
    for (int t = 0; t < 9; ++t) {
        if (t < 8) loadB(t + 1, (t + 1) & 1);
        const unsigned short* bp = &sB[t & 1][0];
        const float bv = bvv[t];
        f32x4 acc0 = {bv, bv, bv, bv}, acc1 = {bv, bv, bv, bv};
#pragma unroll
        for (int u = 0; u < 9; ++u) {
            bf16x8 b = *(const bf16x8*)&bp[(u * 64 + l) * 8];
            acc0 = __builtin_amdgcn_mfma_f32_16x16x32_bf16(a0[u], b, acc0, 0, 0, 0);
            acc1 = __builtin_amdgcn_mfma_f32_16x16x32_bf16(a1[u], b, acc1, 0, 0, 0);
        }
        const size_t tb = ((size_t)t * BN + bz) * HW;
#pragma unroll
        for (int r = 0; r < 4; ++r) {
            int x = bx * 16 + 4 * q + r;
            if (yA < H && x < W)
                offbuf[(tb + (size_t)yA * W + x) * 16 + j16] = f2bf(fmaxf(acc0[r], 0.f));
            if (yB < H && x < W)
                offbuf[(tb + (size_t)yB * W + x) * 16 + j16] = f2bf(fmaxf(acc1[r], 0.f));
        }
        __syncthreads();
    }
}

// ---------------- deformable conv: LDS window fast path + global fallback ----------------
__global__ __launch_bounds__(256) void deform_kernel(
    const float* __restrict__ unrP, const unsigned short* __restrict__ offbuf,
    const float* __restrict__ dwT, const float* __restrict__ dcn_b,
    float* __restrict__ out, int bbBase, int BN, int H, int W)
{
    // window: rows/cols [A.. A+19] (clamped at image edges), pair-interleaved:
    // sTile[((g*400 + r*20 + c))*2 + d] = pU[ch=2g+d][clamp(Ay+r)][clamp(Ax+c)]
    __shared__ float sTile[8 * 400 * 2];   // 25600 B
    const int tx = threadIdx.x & 15, ty = threadIdx.x >> 4;
    int bxs, bys, bz;
    xcd_swz(bxs, bys, bz);
    const int bb = bbBase + bz;
    const int xr = bxs * 16 + tx, yr = bys * 16 + ty;
    const int x = min(xr, W - 1), y = min(yr, H - 1);
    const size_t HW = (size_t)H * W;
    const float* base = unrP + (size_t)bb * 16 * HW;
    const size_t pxi = (size_t)y * W + x;
    const int Ax = bxs * 16 - 1, Ay = bys * 16 - 1;

    for (int idx = threadIdx.x; idx < 6400; idx += 256) {
        int ch = idx / 400, rc = idx - ch * 400;
        int r = rc / 20, cx = rc - r * 20;
        int gy = min(max(Ay + r, 0), H - 1);
        int gx = min(max(Ax + cx, 0), W - 1);
        sTile[((ch >> 1) * 400 + rc) * 2 + (ch & 1)] =
            base[(size_t)ch * HW + (size_t)gy * W + gx];
    }
    __syncthreads();

    f32x4 pv[4];
#pragma unroll
    for (int i = 0; i < 4; ++i)
        pv[i] = (f32x4){dcn_b[4 * i], dcn_b[4 * i + 1], dcn_b[4 * i + 2], dcn_b[4 * i + 3]};

#pragma unroll 1
    for (int k = 0; k < 9; ++k) {
        const unsigned short* po = offbuf + (((size_t)k * BN + bz) * HW + pxi) * 16;
        bf16x8 s0 = *(const bf16x8*)(po);
        bf16x8 s1 = *(const bf16x8*)(po + 8);
        float ov[16];
#pragma unroll
        for (int i = 0; i < 8; ++i) ov[i] = bf2f((unsigned short)s0[i]);
#pragma unroll
        for (int i = 0; i < 8; ++i) ov[8 + i] = bf2f((unsigned short)s1[i]);

        const float fy = (float)(y - 1 + k / 3);
        const float fx = (float)(x - 1 + k % 3);
#pragma unroll
        for (int g = 0; g < 8; ++g) {
            float oy = ov[2 * g], ox = ov[2 * g + 1];
            float ys = fy + oy, xs = fx + ox;
            float y0f = floorf(ys), x0f = floorf(xs);
            float dy = ys - y0f, dx = xs - x0f;
            int iy0 = (int)y0f, ix0 = (int)x0f;
            int iy1 = iy0 + 1, ix1 = ix0 + 1;
            float vy0 = (iy0 >= 0 && iy0 < H) ? 1.f : 0.f;
            float vy1 = (iy1 >= 0 && iy1 < H) ? 1.f : 0.f;
            float vx0 = (ix0 >= 0 && ix0 < W) ? 1.f : 0.f;
            float vx1 = (ix1 < W) ? 1.f : 0.f;            // ix1 >= 0 always (relu)
            float wx0 = (1.f - dx) * vx0, wx1 = dx * vx1;
            float wy0 = (1.f - dy) * vy0, wy1 = dy * vy1;

            const int tiy0 = iy0 - Ay, tix0 = ix0 - Ax;   // >= 0 by construction
            float v0, v1;
            if (__all(tiy0 <= 18 && tix0 <= 18)) {
                // LDS path: staged clamped window == global clamped reads
                const float* tg = &sTile[(g * 400) * 2];
                const int i00 = (tiy0 * 20 + tix0) * 2;
                f32x2 c00 = *(const f32x2*)&tg[i00];
                f32x2 c01 = *(const f32x2*)&tg[i00 + 2];
                f32x2 c10 = *(const f32x2*)&tg[i00 + 40];
                f32x2 c11 = *(const f32x2*)&tg[i00 + 42];
                f32x2 vv = (wy0 * wx0) * c00 + (wy0 * wx1) * c01
                         + (wy1 * wx0) * c10 + (wy1 * wx1) * c11;
                v0 = vv.x; v1 = vv.y;
            } else {
                // global fallback (R11 verbatim)
                int pb = min(max(ix0, 0), W - 2);
                const bool swp = (ix0 != pb);
                float wA = swp ? wx1 : wx0;
                float wB = swp ? wx0 : wx1;
                int cy0 = min(max(iy0, 0), H - 1), cy1 = min(max(iy1, 0), H - 1);
                const float* p0 = base + (size_t)(2 * g) * HW;
                const float* p1 = base + (size_t)(2 * g + 1) * HW;
                const int ib0 = cy0 * W + pb, ib1 = cy1 * W + pb;
                f32x2 a0 = ld2(p0 + ib0), a1 = ld2(p0 + ib1);
                f32x2 b0 = ld2(p1 + ib0), b1 = ld2(p1 + ib1);
                float wA0 = wy0 * wA, wB0 = wy0 * wB, wA1 = wy1 * wA, wB1 = wy1 * wB;
                v0 = wA0 * a0.x + wB0 * a0.y + wA1 * a1.x + wB1 * a1.y;
                v1 = wA0 * b0.x + wB0 * b0.y + wA1 * b1.x + wB1 * b1.y;
            }
            const f32x4* wv0 = (const f32x4*)(dwT + ((2 * g) * 9 + k) * 16);
            const f32x4* wv1 = (const f32x4*)(dwT + ((2 * g + 1) * 9 + k) * 16);
#pragma unroll
            for (int i = 0; i < 4; ++i) pv[i] += v0 * wv0[i];
#pragma unroll
            for (int i = 0; i < 4; ++i) pv[i] += v1 * wv1[i];
        }
    }

    if (xr < W && yr < H) {
#pragma unroll
        for (int i = 0; i < 4; ++i)
#pragma unroll
            for (int c = 0; c < 4; ++c)
                out[((size_t)(bb * 16 + 4 * i + c) * H + y) * W + x] = pv[i][c];
    }
}

extern "C" void kernel_launch(void* const* d_in, const int* in_sizes, int n_in,
                              void* d_out, int out_size, void* d_ws, size_t ws_size,
                              hipStream_t stream) {
    (void)in_sizes; (void)n_in; (void)out_size;
    const float* ref = (const float*)d_in[0];
    const float* unr = (const float*)d_in[1];
    const float* c1w = (const float*)d_in[2];  const float* c1b = (const float*)d_in[3];
    const float* c2w = (const float*)d_in[4];  const float* c2b = (const float*)d_in[5];
    const float* c3w = (const float*)d_in[6];  const float* c3b = (const float*)d_in[7];
    const float* o1w = (const float*)d_in[8];  const float* o1b = (const float*)d_in[9];
    const float* o2w = (const float*)d_in[10]; const float* o2b = (const float*)d_in[11];
    const float* o3w = (const float*)d_in[12]; const float* o3b = (const float*)d_in[13];
    const float* dw  = (const float*)d_in[14]; const float* db  = (const float*)d_in[15];

    float* out0 = (float*)d_out;
    float* out1 = out0 + (size_t)4 * 16 * 256 * 256;
    float* out2 = out1 + (size_t)4 * 16 * 254 * 254;

    unsigned short* fA = (unsigned short*)d_ws;       // 4*65536*16 bf16
    unsigned short* fB = fA + (size_t)4 * 65536 * 16;
    unsigned short* fC = fB + (size_t)4 * 65536 * 16; // 4*64516*16 bf16
    unsigned short* fD = fC + (size_t)4 * 64516 * 16;
    float* pU = (float*)(fD + (size_t)4 * 64516 * 16);  // planar unr f32, 4*16*65536
    unsigned short* BfragBase = (unsigned short*)(pU + (size_t)4 * 16 * 65536);
    unsigned short* Bc16 = BfragBase + 3 * 41472;     // 2*2560 bf16
    float* biasPrep = (float*)(Bc16 + 2 * 2560);
    float* dwT = biasPrep + 3 * 144;
    unsigned short* offbuf = (unsigned short*)(dwT + 2304);

    const size_t used = (size_t)((char*)offbuf - (char*)d_ws);
    const size_t slice1 = (size_t)256 * 256 * 144;
    const int NB = (ws_size >= used + 4 * slice1 * 2) ? 4 : 1;

    dim3 blk(16, 16);
    prep_kernel<<<dim3(81, 3), 512, 0, stream>>>(o1w, o2w, o3w, o1b, o2b, o3b,
                                                 dw, c2w, c3w,
                                                 BfragBase, biasPrep, dwT, Bc16);
    conv1_kernel<<<dim3(16, 16, 8), blk, 0, stream>>>(ref, unr, c1w, c1b, fA, fB, pU);

    for (int lvl = 0; lvl < 3; ++lvl) {
        const unsigned short *rf, *uf; float* o; int H;
        const unsigned short* Bf = BfragBase + lvl * 41472;
        const float* bp = biasPrep + lvl * 144;
        if (lvl == 0) { rf = fA; uf = fB; o = out0; H = 256; }
        else if (lvl == 1) { rf = fC; uf = fD; o = out1; H = 254; }
        else { rf = fA; uf = fB; o = out2; H = 252; }

        if (NB == 4) {
            offconv_kernel<<<dim3(16, 16, 4), 512, 0, stream>>>(rf, uf, Bf, bp, offbuf, 0, 4, H, H);
            deform_kernel<<<dim3(16, 16, 4), 256, 0, stream>>>(pU, offbuf, dwT, db, o, 0, 4, H, H);
        } else {
            for (int b = 0; b < 4; ++b) {
                offconv_kernel<<<dim3(16, 16, 1), 512, 0, stream>>>(rf, uf, Bf, bp, offbuf, b, 1, H, H);
                deform_kernel<<<dim3(16, 16, 1), 256, 0, stream>>>(pU, offbuf, dwT, db, o, b, 1, H, H);
            }
        }

        if (lvl == 0) {
            c16m_kernel<<<dim3(16, 16, 8), 512, 0, stream>>>(fA, fB, Bc16, c2b, fC, fD, pU, 254, 254);
        } else if (lvl == 1) {
            c16m_kernel<<<dim3(16, 16, 8), 512, 0, stream>>>(fC, fD, Bc16 + 2560, c3b, fA, fB, pU, 252, 252);
        }
    }
}

// Round 16
// 307.369 us; speedup vs baseline: 1.1666x; 1.1666x over previous
//
#include <hip/hip_runtime.h>

// B=4, C=16, G=8, KK=9.  Levels: 256x256, 254x254, 252x252.
// Feature maps: channel-last BF16 [b][px][16]; unr features ALSO planar f32
// [b][c][y][x] for deform gather (R5/R7-proven).
// deform R16: sampling as R13 (1 thr/px, planar fused x-pair), einsum via MFMA
// (K=144->160 in 5 chunks of 32; kk = g*4 + tl*2 + d; A panel in LDS).

typedef __attribute__((ext_vector_type(8))) short bf16x8;
typedef __attribute__((ext_vector_type(4))) float f32x4;
typedef __attribute__((ext_vector_type(2))) float f32x2;

__device__ inline unsigned short f2bf(float f) {
    union { float f; unsigned int u; } x; x.f = f;
    unsigned int u = x.u;
    u += 0x7fffu + ((u >> 16) & 1u);   // RNE
    return (unsigned short)(u >> 16);
}
__device__ inline float bf2f(unsigned short u) {
    union { unsigned int i; float f; } x; x.i = ((unsigned int)u) << 16;
    return x.f;
}
__device__ inline f32x2 ld2(const float* p) {   // 8B load, 4B-align safe
    f32x2 v;
    __builtin_memcpy(&v, p, 8);
    return v;
}

// Bijective XCD-aware block swizzle (T1).  Requires nwg % 8 == 0.
__device__ inline void xcd_swz(int& bx, int& by, int& bz) {
    const int gx = gridDim.x, gy = gridDim.y, gz = gridDim.z;
    const int hw = blockIdx.x + gx * (blockIdx.y + gy * blockIdx.z);
    const int per = (gx * gy * gz) >> 3;
    const int lg = (hw & 7) * per + (hw >> 3);
    bz = lg / (gx * gy);
    const int rem = lg - bz * gx * gy;
    by = rem / gx;
    bx = rem - by * gx;
}

// ---------------- conv1: 3->16, pad1, relu; both images in one launch ----------------
__global__ __launch_bounds__(256) void conv1_kernel(
    const float* __restrict__ ref, const float* __restrict__ unr,
    const float* __restrict__ w, const float* __restrict__ bias,
    unsigned short* __restrict__ outA, unsigned short* __restrict__ outB,
    float* __restrict__ pU)
{
    const int H = 256, W = 256;
    __shared__ float sIn[3][18][18];
    const int tx = threadIdx.x, ty = threadIdx.y;
    const int tid = ty * 16 + tx;
    const int bx = blockIdx.x, by = blockIdx.y, bz8 = blockIdx.z;
    const int isUnr = bz8 >> 2, bb = bz8 & 3;
    const float* in = isUnr ? unr : ref;
    unsigned short* outCL = isUnr ? outB : outA;
    const int x0 = bx * 16 - 1, y0 = by * 16 - 1;

    for (int idx = tid; idx < 3 * 324; idx += 256) {
        int c = idx / 324, rem = idx % 324, r = rem / 18, col = rem % 18;
        int gy = y0 + r, gx = x0 + col;
        float v = 0.f;
        if (gy >= 0 && gy < H && gx >= 0 && gx < W)
            v = in[((bb * 3 + c) * H + gy) * W + gx];
        sIn[c][r][col] = v;
    }
    __syncthreads();

    const int y = by * 16 + ty, x = bx * 16 + tx;
    float acc[16];
#pragma unroll
    for (int o = 0; o < 16; o++) acc[o] = bias[o];
#pragma unroll
    for (int ci = 0; ci < 3; ci++) {
        float xv[9];
#pragma unroll
        for (int r = 0; r < 3; r++)
#pragma unroll
            for (int c = 0; c < 3; c++)
                xv[r * 3 + c] = sIn[ci][ty + r][tx + c];
#pragma unroll
        for (int o = 0; o < 16; o++) {
            const float* wp = w + (o * 3 + ci) * 9;
#pragma unroll
            for (int u = 0; u < 9; u++) acc[o] += wp[u] * xv[u];
        }
    }
#pragma unroll
    for (int o = 0; o < 16; o++) acc[o] = fmaxf(acc[o], 0.f);

    const size_t HW = (size_t)H * W;
    unsigned short tmp[16];
#pragma unroll
    for (int o = 0; o < 16; o++) tmp[o] = f2bf(acc[o]);
    unsigned short* op = outCL + ((size_t)bb * HW + (size_t)y * W + x) * 16;
    *(bf16x8*)(op) = *(bf16x8*)&tmp[0];
    *(bf16x8*)(op + 8) = *(bf16x8*)&tmp[8];
    if (isUnr) {
#pragma unroll
        for (int o = 0; o < 16; o++)
            pU[((size_t)(bb * 16 + o) * H + y) * W + x] = acc[o];
    }
}

// ---------------- MFMA conv 16->16, pad0, relu; bf16 CL in/out; both images ----------------
__global__ __launch_bounds__(512, 4) void c16m_kernel(
    const unsigned short* __restrict__ inA, const unsigned short* __restrict__ inB,
    const unsigned short* __restrict__ Bc16, const float* __restrict__ bias,
    unsigned short* __restrict__ outA, unsigned short* __restrict__ outB,
    float* __restrict__ pU, int Hout, int Wout)
{
    const int Hin = Hout + 2, Win = Wout + 2;
    __shared__ __align__(16) unsigned short sC[324 * 16];
    __shared__ float sT[16][16][17];
    const int tid = threadIdx.x;
    const int bx = blockIdx.x, by = blockIdx.y, bz8 = blockIdx.z;
    const int isUnr = bz8 >> 2, bz = bz8 & 3;
    const unsigned short* inCL = isUnr ? inB : inA;
    unsigned short* outCL = isUnr ? outB : outA;
    const int x0 = bx * 16, y0 = by * 16;

    for (int idx = tid; idx < 648; idx += 512) {
        int px = idx >> 1, half = idx & 1;
        int r = px / 18, c = px % 18;
        int gy = min(y0 + r, Hin - 1), gx = min(x0 + c, Win - 1);
        const bf16x8* p = (const bf16x8*)(inCL +
            (((size_t)bz * Hin * Win + (size_t)gy * Win + gx) * 16 + 8 * half));
        *(bf16x8*)&sC[px * 16 + 8 * half] = *p;
    }
    __syncthreads();

    const int w = tid >> 6, l = tid & 63;
    const int q = l >> 4, j16 = l & 15;
    const float bv = bias[j16];
    f32x4 acc0 = {bv, bv, bv, bv}, acc1 = {bv, bv, bv, bv};

#pragma unroll
    for (int t = 0; t < 5; ++t) {
        const int u = (t == 4) ? 8 : 2 * t + (q >> 1);
        const int dr = u / 3, dc = u % 3;
        bf16x8 a0 = *(const bf16x8*)&sC[(((w) + dr) * 18 + (j16 + dc)) * 16 + (q & 1) * 8];
        bf16x8 a1 = *(const bf16x8*)&sC[(((w + 8) + dr) * 18 + (j16 + dc)) * 16 + (q & 1) * 8];
        bf16x8 b = *(const bf16x8*)&Bc16[(t * 64 + l) * 8];
        acc0 = __builtin_amdgcn_mfma_f32_16x16x32_bf16(a0, b, acc0, 0, 0, 0);
        acc1 = __builtin_amdgcn_mfma_f32_16x16x32_bf16(a1, b, acc1, 0, 0, 0);
    }
#pragma unroll
    for (int r = 0; r < 4; ++r) { acc0[r] = fmaxf(acc0[r], 0.f); acc1[r] = fmaxf(acc1[r], 0.f); }

    const int yA = y0 + w, yB = y0 + w + 8;
    const size_t HWo = (size_t)Hout * Wout;
#pragma unroll
    for (int r = 0; r < 4; ++r) {
        int x = x0 + 4 * q + r;
        if (yA < Hout && x < Wout)
            outCL[((size_t)bz * HWo + (size_t)yA * Wout + x) * 16 + j16] = f2bf(acc0[r]);
        if (yB < Hout && x < Wout)
            outCL[((size_t)bz * HWo + (size_t)yB * Wout + x) * 16 + j16] = f2bf(acc1[r]);
    }

    if (isUnr) {
#pragma unroll
        for (int r = 0; r < 4; ++r) {
            sT[w][j16][4 * q + r] = acc0[r];
            sT[w + 8][j16][4 * q + r] = acc1[r];
        }
        __syncthreads();
        const int ch = tid >> 5, yy = (tid >> 1) & 15, half = tid & 1;
        const int yo = y0 + yy;
        if (yo < Hout) {
            float* dst = pU + ((size_t)(bz * 16 + ch) * Hout + yo) * Wout + x0 + half * 8;
#pragma unroll
            for (int i = 0; i < 8; ++i) {
                int x = x0 + half * 8 + i;
                if (x < Wout) dst[i] = sT[yy][ch][half * 8 + i];
            }
        }
    }
}

// ---------------- weight prep ----------------
__global__ __launch_bounds__(512) void prep_kernel(
    const float* __restrict__ o1w, const float* __restrict__ o2w, const float* __restrict__ o3w,
    const float* __restrict__ o1b, const float* __restrict__ o2b, const float* __restrict__ o3b,
    const float* __restrict__ dw, const float* __restrict__ c2w, const float* __restrict__ c3w,
    unsigned short* __restrict__ Bfrag, float* __restrict__ biasPrep,
    unsigned short* __restrict__ Bc16, unsigned short* __restrict__ dwB)
{
    const int lvl = blockIdx.y;
    const float* Wt = (lvl == 0) ? o1w : (lvl == 1) ? o2w : o3w;
    const float* Bb = (lvl == 0) ? o1b : (lvl == 1) ? o2b : o3b;
    int idx = blockIdx.x * 512 + threadIdx.x;   // 81*512 = 41472
    int j = idx & 7;
    int l = (idx >> 3) & 63;
    int tu = idx >> 9;
    int t = tu / 9, u = tu % 9;
    int q = l >> 4, n16 = l & 15;
    int ci = 8 * q + j;
    int g = n16 >> 1, d = n16 & 1;
    int ch = g * 18 + t * 2 + d;
    Bfrag[lvl * 41472 + idx] = f2bf(Wt[(ch * 32 + ci) * 9 + u]);
    if (blockIdx.x == 0 && threadIdx.x < 144) {
        int n = threadIdx.x;
        int tt = n >> 4, nn = n & 15;
        biasPrep[lvl * 144 + n] = Bb[(nn >> 1) * 18 + tt * 2 + (nn & 1)];
    }
    if (lvl == 0 && blockIdx.x == 1) {
        // deform einsum B-fragments: kk = g*4 + tl*2 + d, t = 2*chunk + tl
        for (int i = threadIdx.x; i < 2560; i += 512) {
            int jj = i & 7, l2 = (i >> 3) & 63, chn = i >> 9;
            int q2 = l2 >> 4, o = l2 & 15;
            int kkl = 8 * q2 + jj;
            int gg = kkl >> 2, tl = (kkl >> 1) & 1, dd = kkl & 1;
            int tt = 2 * chn + tl, cc = 2 * gg + dd;
            float val = (tt < 9) ? dw[(o * 16 + cc) * 9 + tt] : 0.f;
            dwB[i] = f2bf(val);
        }
    }
    if (lvl == 2 && blockIdx.x >= 20 && blockIdx.x < 30) {
        int i2 = (blockIdx.x - 20) * 512 + threadIdx.x;   // 5120 = 2*2560
        int cw = i2 / 2560, rem = i2 % 2560;
        int jj = rem & 7, ll = (rem >> 3) & 63, tt = rem >> 9;
        int qq = ll >> 4, oo = ll & 15;
        int uu = (tt == 4) ? 8 : 2 * tt + (qq >> 1);
        int cc = (qq & 1) * 8 + jj;
        const float* wsel = cw ? c3w : c2w;
        float val = (tt == 4 && qq >= 2) ? 0.f : wsel[(oo * 16 + cc) * 9 + uu];
        Bc16[i2] = f2bf(val);
    }
}

// ---------------- MFMA offset conv -> bf16 offsets [tap][px][16]; B-panel in LDS ----------------
#define CP 40
__global__ __launch_bounds__(512, 4) void offconv_kernel(
    const unsigned short* __restrict__ refCL, const unsigned short* __restrict__ unrCL,
    const unsigned short* __restrict__ Bfrag, const float* __restrict__ biasPrep,
    unsigned short* __restrict__ offbuf, int bbBase, int BN, int H, int W)
{
    __shared__ __align__(16) unsigned short sIn[18 * 18 * CP];
    __shared__ __align__(16) unsigned short sB[2][4608];
    const int tid = threadIdx.x;
    int bx, by, bz;
    xcd_swz(bx, by, bz);
    const int bb = bbBase + bz;
    const int x0 = bx * 16 - 1, y0 = by * 16 - 1;
    const size_t HW = (size_t)H * W;

    auto loadB = [&](int t, int buf) {
        const bf16x8* src = (const bf16x8*)(Bfrag + (size_t)t * 4608);
        bf16x8* dst = (bf16x8*)&sB[buf][0];
        dst[tid] = src[tid];
        if (tid < 64) dst[512 + tid] = src[512 + tid];
    };
    loadB(0, 0);

    for (int idx = tid; idx < 1296; idx += 512) {
        int px = idx >> 2, ch8 = idx & 3;
        int r = px / 18, c = px % 18;
        int gy = y0 + r, gx = x0 + c;
        bf16x8 v = {};
        if (gy >= 0 && gy < H && gx >= 0 && gx < W) {
            const unsigned short* src = (ch8 < 2) ? refCL : unrCL;
            v = *(const bf16x8*)(src + (((size_t)bb * HW + (size_t)gy * W + gx) * 16 + (ch8 & 1) * 8));
        }
        *(bf16x8*)&sIn[px * CP + ch8 * 8] = v;
    }
    __syncthreads();

    const int w = tid >> 6, l = tid & 63;
    const int q = l >> 4, j16 = l & 15;

    bf16x8 a0[9], a1[9];
#pragma unroll
    for (int u = 0; u < 9; ++u) {
        int dr = u / 3, dc = u % 3;
        a0[u] = *(const bf16x8*)&sIn[((w + dr) * 18 + (j16 + dc)) * CP + 8 * q];
        a1[u] = *(const bf16x8*)&sIn[((w + 8 + dr) * 18 + (j16 + dc)) * CP + 8 * q];
    }
    const int yA = by * 16 + w, yB = by * 16 + w + 8;

    float bvv[9];
#pragma unroll
    for (int t = 0; t < 9; ++t) bvv[t] = biasPrep[t * 16 + j16];

#pragma unroll 1
    for (int t = 0; t < 9; ++t) {
        if (t < 8) loadB(t + 1, (t + 1) & 1);
        const unsigned short* bp = &sB[t & 1][0];
        const float bv = bvv[t];
        f32x4 acc0 = {bv, bv, bv, bv}, acc1 = {bv, bv, bv, bv};
#pragma unroll
        for (int u = 0; u < 9; ++u) {
            bf16x8 b = *(const bf16x8*)&bp[(u * 64 + l) * 8];
            acc0 = __builtin_amdgcn_mfma_f32_16x16x32_bf16(a0[u], b, acc0, 0, 0, 0);
            acc1 = __builtin_amdgcn_mfma_f32_16x16x32_bf16(a1[u], b, acc1, 0, 0, 0);
        }
        const size_t tb = ((size_t)t * BN + bz) * HW;
#pragma unroll
        for (int r = 0; r < 4; ++r) {
            int x = bx * 16 + 4 * q + r;
            if (yA < H && x < W)
                offbuf[(tb + (size_t)yA * W + x) * 16 + j16] = f2bf(fmaxf(acc0[r], 0.f));
            if (yB < H && x < W)
                offbuf[(tb + (size_t)yB * W + x) * 16 + j16] = f2bf(fmaxf(acc1[r], 0.f));
        }
        __syncthreads();
    }
}

// ---------------- deformable conv: R13 sampling + MFMA einsum ----------------
__global__ __launch_bounds__(256) void deform_kernel(
    const float* __restrict__ unrP, const unsigned short* __restrict__ offbuf,
    const unsigned short* __restrict__ dwB, const float* __restrict__ dcn_b,
    float* __restrict__ out, int bbBase, int BN, int H, int W)
{
    __shared__ __align__(16) unsigned int sA[256 * 20];   // 20 KB A-panel; reused as sT
    const int tid = threadIdx.x;
    const int tx = tid & 15, ty = tid >> 4;
    int bxs, bys, bz;
    xcd_swz(bxs, bys, bz);
    const int bb = bbBase + bz;
    const int xr = bxs * 16 + tx, yr = bys * 16 + ty;
    const int x = min(xr, W - 1), y = min(yr, H - 1);
    const size_t HW = (size_t)H * W;
    const float* base = unrP + (size_t)bb * 16 * HW;
    const size_t pxi = (size_t)y * W + x;

    const int wv = tid >> 6, l = tid & 63, q = l >> 4, j16 = l & 15;
    const float bvb = dcn_b[j16];
    f32x4 acc0 = {bvb, bvb, bvb, bvb}, acc1 = acc0, acc2 = acc0, acc3 = acc0;

#pragma unroll 1
    for (int chn = 0; chn < 5; ++chn) {
#pragma unroll
        for (int tl = 0; tl < 2; ++tl) {
            const int t = 2 * chn + tl;
            if (t < 9) {
                const unsigned short* po = offbuf + (((size_t)t * BN + bz) * HW + pxi) * 16;
                bf16x8 s0 = *(const bf16x8*)(po);
                bf16x8 s1 = *(const bf16x8*)(po + 8);
                float ov[16];
#pragma unroll
                for (int i = 0; i < 8; ++i) ov[i] = bf2f((unsigned short)s0[i]);
#pragma unroll
                for (int i = 0; i < 8; ++i) ov[8 + i] = bf2f((unsigned short)s1[i]);

                const float fy = (float)(y - 1 + t / 3);
                const float fx = (float)(x - 1 + t % 3);
#pragma unroll
                for (int g = 0; g < 8; ++g) {
                    float oy = ov[2 * g], ox = ov[2 * g + 1];
                    float ys = fy + oy, xs = fx + ox;
                    float y0f = floorf(ys), x0f = floorf(xs);
                    float dy = ys - y0f, dx = xs - x0f;
                    int iy0 = (int)y0f, ix0 = (int)x0f;
                    int iy1 = iy0 + 1, ix1 = ix0 + 1;
                    float vy0 = (iy0 >= 0 && iy0 < H) ? 1.f : 0.f;
                    float vy1 = (iy1 >= 0 && iy1 < H) ? 1.f : 0.f;
                    float vx0 = (ix0 >= 0 && ix0 < W) ? 1.f : 0.f;
                    float vx1 = (ix1 < W) ? 1.f : 0.f;    // ix1 >= 0 always (relu)
                    int pb = min(max(ix0, 0), W - 2);
                    const bool swp = (ix0 != pb);
                    float wx0 = (1.f - dx) * vx0, wx1 = dx * vx1;
                    float wA = swp ? wx1 : wx0;
                    float wB = swp ? wx0 : wx1;
                    float wy0 = (1.f - dy) * vy0, wy1 = dy * vy1;
                    int cy0 = min(max(iy0, 0), H - 1), cy1 = min(max(iy1, 0), H - 1);
                    const float* p0 = base + (size_t)(2 * g) * HW;
                    const float* p1 = base + (size_t)(2 * g + 1) * HW;
                    const int ib0 = cy0 * W + pb, ib1 = cy1 * W + pb;
                    f32x2 a0 = ld2(p0 + ib0), a1 = ld2(p0 + ib1);
                    f32x2 b0 = ld2(p1 + ib0), b1 = ld2(p1 + ib1);
                    float wA0 = wy0 * wA, wB0 = wy0 * wB, wA1 = wy1 * wA, wB1 = wy1 * wB;
                    float v0 = wA0 * a0.x + wB0 * a0.y + wA1 * a1.x + wB1 * a1.y;
                    float v1 = wA0 * b0.x + wB0 * b0.y + wA1 * b1.x + wB1 * b1.y;
                    // kk = g*4 + tl*2 + d -> u32 index g*2 + tl holds (d0, d1)
                    sA[tid * 20 + g * 2 + tl] =
                        (unsigned int)f2bf(v0) | ((unsigned int)f2bf(v1) << 16);
                }
            } else {
#pragma unroll
                for (int g = 0; g < 8; ++g) sA[tid * 20 + g * 2 + tl] = 0u;
            }
        }
        __syncthreads();
        // MFMA: wave wv handles M-groups m = 4wv..4wv+3
        bf16x8 b = *(const bf16x8*)((const unsigned short*)dwB + (size_t)(chn * 64 + l) * 8);
        {
            bf16x8 a;
            a = *(const bf16x8*)&sA[((4 * wv + 0) * 16 + j16) * 20 + 4 * q];
            acc0 = __builtin_amdgcn_mfma_f32_16x16x32_bf16(a, b, acc0, 0, 0, 0);
            a = *(const bf16x8*)&sA[((4 * wv + 1) * 16 + j16) * 20 + 4 * q];
            acc1 = __builtin_amdgcn_mfma_f32_16x16x32_bf16(a, b, acc1, 0, 0, 0);
            a = *(const bf16x8*)&sA[((4 * wv + 2) * 16 + j16) * 20 + 4 * q];
            acc2 = __builtin_amdgcn_mfma_f32_16x16x32_bf16(a, b, acc2, 0, 0, 0);
            a = *(const bf16x8*)&sA[((4 * wv + 3) * 16 + j16) * 20 + 4 * q];
            acc3 = __builtin_amdgcn_mfma_f32_16x16x32_bf16(a, b, acc3, 0, 0, 0);
        }
        __syncthreads();
    }

    // transpose D -> sT (reuse sA): D row = px = m*16 + 4q + r, col = o = j16
    unsigned int* sT = sA;
#pragma unroll
    for (int r = 0; r < 4; ++r) {
        union { float f; unsigned int u; } cvt;
        cvt.f = acc0[r]; sT[((4 * wv + 0) * 16 + 4 * q + r) * 17 + j16] = cvt.u;
        cvt.f = acc1[r]; sT[((4 * wv + 1) * 16 + 4 * q + r) * 17 + j16] = cvt.u;
        cvt.f = acc2[r]; sT[((4 * wv + 2) * 16 + 4 * q + r) * 17 + j16] = cvt.u;
        cvt.f = acc3[r]; sT[((4 * wv + 3) * 16 + 4 * q + r) * 17 + j16] = cvt.u;
    }
    __syncthreads();

    if (xr < W && yr < H) {
#pragma unroll
        for (int o = 0; o < 16; ++o) {
            union { unsigned int u; float f; } cvt;
            cvt.u = sT[tid * 17 + o];
            out[((size_t)(bb * 16 + o) * H + y) * W + x] = cvt.f;
        }
    }
}

extern "C" void kernel_launch(void* const* d_in, const int* in_sizes, int n_in,
                              void* d_out, int out_size, void* d_ws, size_t ws_size,
                              hipStream_t stream) {
    (void)in_sizes; (void)n_in; (void)out_size;
    const float* ref = (const float*)d_in[0];
    const float* unr = (const float*)d_in[1];
    const float* c1w = (const float*)d_in[2];  const float* c1b = (const float*)d_in[3];
    const float* c2w = (const float*)d_in[4];  const float* c2b = (const float*)d_in[5];
    const float* c3w = (const float*)d_in[6];  const float* c3b = (const float*)d_in[7];
    const float* o1w = (const float*)d_in[8];  const float* o1b = (const float*)d_in[9];
    const float* o2w = (const float*)d_in[10]; const float* o2b = (const float*)d_in[11];
    const float* o3w = (const float*)d_in[12]; const float* o3b = (const float*)d_in[13];
    const float* dw  = (const float*)d_in[14]; const float* db  = (const float*)d_in[15];

    float* out0 = (float*)d_out;
    float* out1 = out0 + (size_t)4 * 16 * 256 * 256;
    float* out2 = out1 + (size_t)4 * 16 * 254 * 254;

    unsigned short* fA = (unsigned short*)d_ws;       // 4*65536*16 bf16
    unsigned short* fB = fA + (size_t)4 * 65536 * 16;
    unsigned short* fC = fB + (size_t)4 * 65536 * 16; // 4*64516*16 bf16
    unsigned short* fD = fC + (size_t)4 * 64516 * 16;
    float* pU = (float*)(fD + (size_t)4 * 64516 * 16);  // planar unr f32
    unsigned short* BfragBase = (unsigned short*)(pU + (size_t)4 * 16 * 65536);
    unsigned short* Bc16 = BfragBase + 3 * 41472;     // 2*2560 bf16
    unsigned short* dwB = Bc16 + 2 * 2560;            // 2560 bf16
    float* biasPrep = (float*)(dwB + 2560);
    unsigned short* offbuf = (unsigned short*)(biasPrep + 3 * 144);

    const size_t used = (size_t)((char*)offbuf - (char*)d_ws);
    const size_t slice1 = (size_t)256 * 256 * 144;
    const int NB = (ws_size >= used + 4 * slice1 * 2) ? 4 : 1;

    dim3 blk(16, 16);
    prep_kernel<<<dim3(81, 3), 512, 0, stream>>>(o1w, o2w, o3w, o1b, o2b, o3b,
                                                 dw, c2w, c3w,
                                                 BfragBase, biasPrep, Bc16, dwB);
    conv1_kernel<<<dim3(16, 16, 8), blk, 0, stream>>>(ref, unr, c1w, c1b, fA, fB, pU);

    for (int lvl = 0; lvl < 3; ++lvl) {
        const unsigned short *rf, *uf; float* o; int H;
        const unsigned short* Bf = BfragBase + lvl * 41472;
        const float* bp = biasPrep + lvl * 144;
        if (lvl == 0) { rf = fA; uf = fB; o = out0; H = 256; }
        else if (lvl == 1) { rf = fC; uf = fD; o = out1; H = 254; }
        else { rf = fA; uf = fB; o = out2; H = 252; }

        if (NB == 4) {
            offconv_kernel<<<dim3(16, 16, 4), 512, 0, stream>>>(rf, uf, Bf, bp, offbuf, 0, 4, H, H);
            deform_kernel<<<dim3(16, 16, 4), 256, 0, stream>>>(pU, offbuf, dwB, db, o, 0, 4, H, H);
        } else {
            for (int b = 0; b < 4; ++b) {
                offconv_kernel<<<dim3(16, 16, 1), 512, 0, stream>>>(rf, uf, Bf, bp, offbuf, b, 1, H, H);
                deform_kernel<<<dim3(16, 16, 1), 256, 0, stream>>>(pU, offbuf, dwB, db, o, b, 1, H, H);
            }
        }

        if (lvl == 0) {
            c16m_kernel<<<dim3(16, 16, 8), 512, 0, stream>>>(fA, fB, Bc16, c2b, fC, fD, pU, 254, 254);
        } else if (lvl == 1) {
            c16m_kernel<<<dim3(16, 16, 8), 512, 0, stream>>>(fC, fD, Bc16 + 2560, c3b, fA, fB, pU, 252, 252);
        }
    }
}